// Round 9
// baseline (2003.671 us; speedup 1.0000x reference)
//
#include <hip/hip_runtime.h>

#define NEGV (-10000.0f)

static constexpr int Bb    = 128;
static constexpr int Tt    = 512;
static constexpr int Mrows = Bb * Tt;   // 65536
static constexpr int Hh    = 50;
static constexpr int Ncols = 400;       // both directions stacked
static constexpr int START = 5;

__device__ __forceinline__ float fsig(float x) {
    return __builtin_amdgcn_rcpf(1.0f + __expf(-x));
}
__device__ __forceinline__ float ftanh(float x) {
    return 2.0f * __builtin_amdgcn_rcpf(1.0f + __expf(-2.0f * x)) - 1.0f;
}

// ---------------------------------------------------------------------------
// GEMM: C[M,N] = A[M,K] @ W[N,K]^T + bias[N]   (unchanged, known-good)
// ---------------------------------------------------------------------------
template <bool GATHER>
__global__ __launch_bounds__(256) void gemm_xg(
    const float* __restrict__ A, const int* __restrict__ idx,
    const float* __restrict__ W, const float* __restrict__ bias,
    float* __restrict__ C, int M, int N, int K)
{
    __shared__ __align__(16) float As[16][68];
    __shared__ __align__(16) float Bs[16][68];

    const int tid = threadIdx.x;
    const int m0 = blockIdx.x * 64;
    const int n0 = blockIdx.y * 64;

    const int lm = tid >> 2;          // 0..63
    const int lk = (tid & 3) * 4;     // 0,4,8,12
    const int col = (tid & 15) * 4;   // 0..60
    const int row = (tid >> 4) * 4;   // 0..60

    float acc[4][4] = {};

    const long arow = m0 + lm;
    const long asrc = GATHER ? (long)idx[arow] : arow;
    const float* Aptr = A + asrc * K;
    const bool wvalid = (n0 + lm) < N;
    const float* Wptr = W + (long)(n0 + lm) * K;

    for (int k0 = 0; k0 < K; k0 += 16) {
        const int k = k0 + lk;
        float4 av = make_float4(0.f, 0.f, 0.f, 0.f);
        float4 bv = make_float4(0.f, 0.f, 0.f, 0.f);
        if (k + 3 < K) {
            av = *(const float4*)(Aptr + k);
        } else {
            if (k + 0 < K) av.x = Aptr[k + 0];
            if (k + 1 < K) av.y = Aptr[k + 1];
            if (k + 2 < K) av.z = Aptr[k + 2];
            if (k + 3 < K) av.w = Aptr[k + 3];
        }
        if (wvalid) {
            if (k + 3 < K) {
                bv = *(const float4*)(Wptr + k);
            } else {
                if (k + 0 < K) bv.x = Wptr[k + 0];
                if (k + 1 < K) bv.y = Wptr[k + 1];
                if (k + 2 < K) bv.z = Wptr[k + 2];
                if (k + 3 < K) bv.w = Wptr[k + 3];
            }
        }
        __syncthreads();
        As[lk + 0][lm] = av.x; As[lk + 1][lm] = av.y;
        As[lk + 2][lm] = av.z; As[lk + 3][lm] = av.w;
        Bs[lk + 0][lm] = bv.x; Bs[lk + 1][lm] = bv.y;
        Bs[lk + 2][lm] = bv.z; Bs[lk + 3][lm] = bv.w;
        __syncthreads();
        #pragma unroll
        for (int kk = 0; kk < 16; ++kk) {
            float4 a = *(const float4*)(&As[kk][row]);
            float4 b = *(const float4*)(&Bs[kk][col]);
            acc[0][0] += a.x * b.x; acc[0][1] += a.x * b.y; acc[0][2] += a.x * b.z; acc[0][3] += a.x * b.w;
            acc[1][0] += a.y * b.x; acc[1][1] += a.y * b.y; acc[1][2] += a.y * b.z; acc[1][3] += a.y * b.w;
            acc[2][0] += a.z * b.x; acc[2][1] += a.z * b.y; acc[2][2] += a.z * b.z; acc[2][3] += a.z * b.w;
            acc[3][0] += a.w * b.x; acc[3][1] += a.w * b.y; acc[3][2] += a.w * b.z; acc[3][3] += a.w * b.w;
        }
    }

    #pragma unroll
    for (int ii = 0; ii < 4; ++ii) {
        const long crow = m0 + row + ii;
        const int c0i = n0 + col;
        if (c0i + 3 < N) {
            float4 v;
            v.x = acc[ii][0] + bias[c0i + 0];
            v.y = acc[ii][1] + bias[c0i + 1];
            v.z = acc[ii][2] + bias[c0i + 2];
            v.w = acc[ii][3] + bias[c0i + 3];
            *(float4*)(C + crow * N + c0i) = v;
        } else {
            #pragma unroll
            for (int jj = 0; jj < 4; ++jj) {
                int cc = c0i + jj;
                if (cc < N) C[crow * N + cc] = acc[ii][jj] + bias[cc];
            }
        }
    }
}

// ---------------------------------------------------------------------------
// LSTM scan: ONE WAVE per (b,dir) chain; ZERO barriers, ZERO cross-wave
// or cross-lane handoff except the h broadcast. Lane u (<50) owns hidden
// unit u end-to-end: all 4 gate-weight rows live as 200 NAMED laundered
// scalars (r8 proved named+launder+waves_per_eu(1,1) => register-resident;
// ~255 regs used of 512). Per step: 13 broadcast ds_read_b128 of h,
// 200 FMAs, activations in-register, hs[u]=h write. The r4-r8 structure's
// poison (pre[] LDS roundtrip + s_barrier lockstep, ~1500cy/step) is gone.
// ---------------------------------------------------------------------------
#define LA10(x0,x1,x2,x3,x4,x5,x6,x7,x8,x9) \
    asm volatile("" : "+v"(x0), "+v"(x1), "+v"(x2), "+v"(x3), "+v"(x4), \
                      "+v"(x5), "+v"(x6), "+v"(x7), "+v"(x8), "+v"(x9))

__global__ void
__attribute__((amdgpu_flat_work_group_size(64, 64), amdgpu_waves_per_eu(1, 1)))
lstm_scan(
    const float* __restrict__ xg,     // [M,400] (bias already added)
    const float* __restrict__ w_hh,   // [2,200,50]
    const float* __restrict__ h0,     // layer base: [2,B,50]
    const float* __restrict__ c0,
    float* __restrict__ xout)         // [M,100], col = dir*50+k
{
    const int b    = blockIdx.x & 127;
    const int dir  = blockIdx.x >> 7;
    const int lane = threadIdx.x;
    const int u    = (lane < 50) ? lane : 49;   // clamp (lanes 50-63 idle-ish)

    __shared__ __align__(16) float hs[52];

    // ---- 200 named scalar weights: rows u, 50+u, 100+u, 150+u ----
    const float* r0 = w_hh + ((long)dir * 200 + u) * 50;   // input gate row
    const float* r1 = r0 + 2500;                           // forget
    const float* r2 = r0 + 5000;                           // cell
    const float* r3 = r0 + 7500;                           // output

    float wa0=r0[0],wa1=r0[1],wa2=r0[2],wa3=r0[3],wa4=r0[4],wa5=r0[5],wa6=r0[6],wa7=r0[7],wa8=r0[8],wa9=r0[9];
    float wa10=r0[10],wa11=r0[11],wa12=r0[12],wa13=r0[13],wa14=r0[14],wa15=r0[15],wa16=r0[16],wa17=r0[17],wa18=r0[18],wa19=r0[19];
    float wa20=r0[20],wa21=r0[21],wa22=r0[22],wa23=r0[23],wa24=r0[24],wa25=r0[25],wa26=r0[26],wa27=r0[27],wa28=r0[28],wa29=r0[29];
    float wa30=r0[30],wa31=r0[31],wa32=r0[32],wa33=r0[33],wa34=r0[34],wa35=r0[35],wa36=r0[36],wa37=r0[37],wa38=r0[38],wa39=r0[39];
    float wa40=r0[40],wa41=r0[41],wa42=r0[42],wa43=r0[43],wa44=r0[44],wa45=r0[45],wa46=r0[46],wa47=r0[47],wa48=r0[48],wa49=r0[49];
    float wf0=r1[0],wf1=r1[1],wf2=r1[2],wf3=r1[3],wf4=r1[4],wf5=r1[5],wf6=r1[6],wf7=r1[7],wf8=r1[8],wf9=r1[9];
    float wf10=r1[10],wf11=r1[11],wf12=r1[12],wf13=r1[13],wf14=r1[14],wf15=r1[15],wf16=r1[16],wf17=r1[17],wf18=r1[18],wf19=r1[19];
    float wf20=r1[20],wf21=r1[21],wf22=r1[22],wf23=r1[23],wf24=r1[24],wf25=r1[25],wf26=r1[26],wf27=r1[27],wf28=r1[28],wf29=r1[29];
    float wf30=r1[30],wf31=r1[31],wf32=r1[32],wf33=r1[33],wf34=r1[34],wf35=r1[35],wf36=r1[36],wf37=r1[37],wf38=r1[38],wf39=r1[39];
    float wf40=r1[40],wf41=r1[41],wf42=r1[42],wf43=r1[43],wf44=r1[44],wf45=r1[45],wf46=r1[46],wf47=r1[47],wf48=r1[48],wf49=r1[49];
    float wg0=r2[0],wg1=r2[1],wg2=r2[2],wg3=r2[3],wg4=r2[4],wg5=r2[5],wg6=r2[6],wg7=r2[7],wg8=r2[8],wg9=r2[9];
    float wg10=r2[10],wg11=r2[11],wg12=r2[12],wg13=r2[13],wg14=r2[14],wg15=r2[15],wg16=r2[16],wg17=r2[17],wg18=r2[18],wg19=r2[19];
    float wg20=r2[20],wg21=r2[21],wg22=r2[22],wg23=r2[23],wg24=r2[24],wg25=r2[25],wg26=r2[26],wg27=r2[27],wg28=r2[28],wg29=r2[29];
    float wg30=r2[30],wg31=r2[31],wg32=r2[32],wg33=r2[33],wg34=r2[34],wg35=r2[35],wg36=r2[36],wg37=r2[37],wg38=r2[38],wg39=r2[39];
    float wg40=r2[40],wg41=r2[41],wg42=r2[42],wg43=r2[43],wg44=r2[44],wg45=r2[45],wg46=r2[46],wg47=r2[47],wg48=r2[48],wg49=r2[49];
    float wo0=r3[0],wo1=r3[1],wo2=r3[2],wo3=r3[3],wo4=r3[4],wo5=r3[5],wo6=r3[6],wo7=r3[7],wo8=r3[8],wo9=r3[9];
    float wo10=r3[10],wo11=r3[11],wo12=r3[12],wo13=r3[13],wo14=r3[14],wo15=r3[15],wo16=r3[16],wo17=r3[17],wo18=r3[18],wo19=r3[19];
    float wo20=r3[20],wo21=r3[21],wo22=r3[22],wo23=r3[23],wo24=r3[24],wo25=r3[25],wo26=r3[26],wo27=r3[27],wo28=r3[28],wo29=r3[29];
    float wo30=r3[30],wo31=r3[31],wo32=r3[32],wo33=r3[33],wo34=r3[34],wo35=r3[35],wo36=r3[36],wo37=r3[37],wo38=r3[38],wo39=r3[39];
    float wo40=r3[40],wo41=r3[41],wo42=r3[42],wo43=r3[43],wo44=r3[44],wo45=r3[45],wo46=r3[46],wo47=r3[47],wo48=r3[48],wo49=r3[49];

    LA10(wa0,wa1,wa2,wa3,wa4,wa5,wa6,wa7,wa8,wa9);
    LA10(wa10,wa11,wa12,wa13,wa14,wa15,wa16,wa17,wa18,wa19);
    LA10(wa20,wa21,wa22,wa23,wa24,wa25,wa26,wa27,wa28,wa29);
    LA10(wa30,wa31,wa32,wa33,wa34,wa35,wa36,wa37,wa38,wa39);
    LA10(wa40,wa41,wa42,wa43,wa44,wa45,wa46,wa47,wa48,wa49);
    LA10(wf0,wf1,wf2,wf3,wf4,wf5,wf6,wf7,wf8,wf9);
    LA10(wf10,wf11,wf12,wf13,wf14,wf15,wf16,wf17,wf18,wf19);
    LA10(wf20,wf21,wf22,wf23,wf24,wf25,wf26,wf27,wf28,wf29);
    LA10(wf30,wf31,wf32,wf33,wf34,wf35,wf36,wf37,wf38,wf39);
    LA10(wf40,wf41,wf42,wf43,wf44,wf45,wf46,wf47,wf48,wf49);
    LA10(wg0,wg1,wg2,wg3,wg4,wg5,wg6,wg7,wg8,wg9);
    LA10(wg10,wg11,wg12,wg13,wg14,wg15,wg16,wg17,wg18,wg19);
    LA10(wg20,wg21,wg22,wg23,wg24,wg25,wg26,wg27,wg28,wg29);
    LA10(wg30,wg31,wg32,wg33,wg34,wg35,wg36,wg37,wg38,wg39);
    LA10(wg40,wg41,wg42,wg43,wg44,wg45,wg46,wg47,wg48,wg49);
    LA10(wo0,wo1,wo2,wo3,wo4,wo5,wo6,wo7,wo8,wo9);
    LA10(wo10,wo11,wo12,wo13,wo14,wo15,wo16,wo17,wo18,wo19);
    LA10(wo20,wo21,wo22,wo23,wo24,wo25,wo26,wo27,wo28,wo29);
    LA10(wo30,wo31,wo32,wo33,wo34,wo35,wo36,wo37,wo38,wo39);
    LA10(wo40,wo41,wo42,wo43,wo44,wo45,wo46,wo47,wo48,wo49);

    const float4* h4 = (const float4*)hs;
    float c = 0.f;
    if (lane < 50) {
        c        = c0[((long)dir * Bb + b) * Hh + lane];
        hs[lane] = h0[((long)dir * Bb + b) * Hh + lane];
    } else if (lane < 52) {
        hs[lane] = 0.f;
    }
    __syncthreads();   // once, before the loop

    const long rowbase = (long)b * Tt;
    const float* xbase = xg + rowbase * 400 + dir * 200 + u;
    float* op = xout + rowbase * 100 + dir * 50 + lane;

    #define TTOF(s) (dir ? (Tt - 1 - (s)) : (s))
    #define XL(s, QI, QF, QG, QO) { \
        const float* p = xbase + (long)TTOF(s) * 400; \
        QI = p[0]; QF = p[50]; QG = p[100]; QO = p[150]; }

    #define QK(Q, A0,A1,A2,A3, F0,F1,F2,F3, G0,G1,G2,G3, O0,O1,O2,O3) { \
        const float4 hv = h4[Q]; \
        sA0 += A0*hv.x + A2*hv.z; sA1 += A1*hv.y + A3*hv.w; \
        sF0 += F0*hv.x + F2*hv.z; sF1 += F1*hv.y + F3*hv.w; \
        sG0 += G0*hv.x + G2*hv.z; sG1 += G1*hv.y + G3*hv.w; \
        sO0 += O0*hv.x + O2*hv.z; sO1 += O1*hv.y + O3*hv.w; }

    #define STEP(QI, QF, QG, QO, TT) do { \
        float sA0 = (QI), sA1 = 0.f, sF0 = (QF), sF1 = 0.f; \
        float sG0 = (QG), sG1 = 0.f, sO0 = (QO), sO1 = 0.f; \
        QK(0,  wa0,wa1,wa2,wa3,     wf0,wf1,wf2,wf3,     wg0,wg1,wg2,wg3,     wo0,wo1,wo2,wo3) \
        QK(1,  wa4,wa5,wa6,wa7,     wf4,wf5,wf6,wf7,     wg4,wg5,wg6,wg7,     wo4,wo5,wo6,wo7) \
        QK(2,  wa8,wa9,wa10,wa11,   wf8,wf9,wf10,wf11,   wg8,wg9,wg10,wg11,   wo8,wo9,wo10,wo11) \
        QK(3,  wa12,wa13,wa14,wa15, wf12,wf13,wf14,wf15, wg12,wg13,wg14,wg15, wo12,wo13,wo14,wo15) \
        QK(4,  wa16,wa17,wa18,wa19, wf16,wf17,wf18,wf19, wg16,wg17,wg18,wg19, wo16,wo17,wo18,wo19) \
        QK(5,  wa20,wa21,wa22,wa23, wf20,wf21,wf22,wf23, wg20,wg21,wg22,wg23, wo20,wo21,wo22,wo23) \
        QK(6,  wa24,wa25,wa26,wa27, wf24,wf25,wf26,wf27, wg24,wg25,wg26,wg27, wo24,wo25,wo26,wo27) \
        QK(7,  wa28,wa29,wa30,wa31, wf28,wf29,wf30,wf31, wg28,wg29,wg30,wg31, wo28,wo29,wo30,wo31) \
        QK(8,  wa32,wa33,wa34,wa35, wf32,wf33,wf34,wf35, wg32,wg33,wg34,wg35, wo32,wo33,wo34,wo35) \
        QK(9,  wa36,wa37,wa38,wa39, wf36,wf37,wf38,wf39, wg36,wg37,wg38,wg39, wo36,wo37,wo38,wo39) \
        QK(10, wa40,wa41,wa42,wa43, wf40,wf41,wf42,wf43, wg40,wg41,wg42,wg43, wo40,wo41,wo42,wo43) \
        QK(11, wa44,wa45,wa46,wa47, wf44,wf45,wf46,wf47, wg44,wg45,wg46,wg47, wo44,wo45,wo46,wo47) \
        { const float4 hv = h4[12]; \
          sA0 += wa48*hv.x; sA1 += wa49*hv.y; \
          sF0 += wf48*hv.x; sF1 += wf49*hv.y; \
          sG0 += wg48*hv.x; sG1 += wg49*hv.y; \
          sO0 += wo48*hv.x; sO1 += wo49*hv.y; } \
        const float gi = fsig(sA0 + sA1); \
        const float gf = fsig(sF0 + sF1); \
        const float gc = ftanh(sG0 + sG1); \
        const float go = fsig(sO0 + sO1); \
        c = gf * c + gi * gc; \
        const float h = go * ftanh(c); \
        if (lane < 50) { \
            hs[lane] = h; \
            op[(long)(TT) * 100] = h; \
        } \
    } while (0)

    float qi0,qf0,qg0,qo0, qi1,qf1,qg1,qo1, qi2,qf2,qg2,qo2, qi3,qf3,qg3,qo3;
    float ni0,nf0,ng0,no0, ni1,nf1,ng1,no1, ni2,nf2,ng2,no2, ni3,nf3,ng3,no3;
    XL(0, qi0,qf0,qg0,qo0) XL(1, qi1,qf1,qg1,qo1)
    XL(2, qi2,qf2,qg2,qo2) XL(3, qi3,qf3,qg3,qo3)
    ni0=nf0=ng0=no0=ni1=nf1=ng1=no1=0.f;
    ni2=nf2=ng2=no2=ni3=nf3=ng3=no3=0.f;

    for (int blk = 0; blk < Tt / 4; ++blk) {
        const int s0i = blk * 4;
        if (blk < Tt / 4 - 1) {   // prefetch next 4 steps (stays in flight)
            XL(s0i + 4, ni0,nf0,ng0,no0) XL(s0i + 5, ni1,nf1,ng1,no1)
            XL(s0i + 6, ni2,nf2,ng2,no2) XL(s0i + 7, ni3,nf3,ng3,no3)
        }
        STEP(qi0,qf0,qg0,qo0, TTOF(s0i + 0));
        STEP(qi1,qf1,qg1,qo1, TTOF(s0i + 1));
        STEP(qi2,qf2,qg2,qo2, TTOF(s0i + 2));
        STEP(qi3,qf3,qg3,qo3, TTOF(s0i + 3));
        qi0=ni0; qf0=nf0; qg0=ng0; qo0=no0;
        qi1=ni1; qf1=nf1; qg1=ng1; qo1=no1;
        qi2=ni2; qf2=nf2; qg2=ng2; qo2=no2;
        qi3=ni3; qf3=nf3; qg3=ng3; qo3=no3;
    }
    #undef STEP
    #undef QK
    #undef XL
    #undef TTOF
}

// ---------------------------------------------------------------------------
// feats[row, i] = (x[row,:] . w_tag[i,:] + b_tag[i]) * mask[row], padded to 8
// ---------------------------------------------------------------------------
__global__ __launch_bounds__(256) void feats_kernel(
    const float* __restrict__ x,      // [M,100]
    const float* __restrict__ w_tag,  // [7,100]
    const float* __restrict__ b_tag,  // [7]
    const float* __restrict__ mask,   // [M]
    float* __restrict__ feats)        // [M,8]
{
    const int gid = blockIdx.x * 256 + threadIdx.x;
    const int row = gid >> 3;
    const int i   = gid & 7;
    if (row >= Mrows) return;
    if (i == 7) { feats[(long)row * 8 + 7] = 0.f; return; }
    const float4* xr = (const float4*)(x + (long)row * 100);
    const float4* wr = (const float4*)(w_tag + (long)i * 100);
    float acc = b_tag[i];
    #pragma unroll
    for (int q = 0; q < 25; ++q) {
        float4 a = xr[q];
        float4 b = wr[q];
        acc += a.x * b.x + a.y * b.y + a.z * b.z + a.w * b.w;
    }
    feats[(long)row * 8 + i] = acc * mask[row];
}

// ---------------------------------------------------------------------------
// Viterbi forward. 8 lanes per batch row (i = lane&7, i<7 active).
// Packs the 7 backpointers of a step into one u32 (3 bits each), stored [T][B].
// ---------------------------------------------------------------------------
__global__ __launch_bounds__(64) void viterbi_fwd(
    const float* __restrict__ feats,   // [M,8]
    const float* __restrict__ trans,   // [7,7]
    unsigned int* __restrict__ bptrw,  // [T*B]
    float* __restrict__ best_score,    // [B] -> d_out
    int* __restrict__ best_tag)        // [B] -> ws
{
    const int lane = threadIdx.x;
    const int sub  = lane >> 3;
    const int i    = lane & 7;
    const int b    = blockIdx.x * 8 + sub;
    const int base = lane & 56;

    float tr[7];
    #pragma unroll
    for (int j = 0; j < 7; ++j) tr[j] = (i < 7) ? trans[i * 7 + j] : -1e30f;

    float score = (i == START) ? 0.0f : NEGV;
    const long fb = (long)b * Tt;

    float featc = feats[(fb + 0) * 8 + i];
    for (int t = 0; t < Tt; ++t) {
        float featn = (t + 1 < Tt) ? feats[(fb + t + 1) * 8 + i] : 0.f;
        float best = -3.4e38f;
        int bp = 0;
        #pragma unroll
        for (int j = 0; j < 7; ++j) {
            float sj = __shfl(score, base | j, 64);
            float m = sj + tr[j];
            if (m > best) { best = m; bp = j; }   // strict > : first-tie like argmax
        }
        if (i < 7) score = best + featc;
        unsigned v = (i < 7) ? ((unsigned)bp << (3 * i)) : 0u;
        v |= __shfl_xor(v, 1, 64);
        v |= __shfl_xor(v, 2, 64);
        v |= __shfl_xor(v, 4, 64);
        if (i == 0) bptrw[(long)t * Bb + b] = v;
        featc = featn;
    }

    float bestv = score;
    int bt = 0;
    #pragma unroll
    for (int j = 1; j < 7; ++j) {
        float sj = __shfl(score, base | j, 64);
        if (i == 0 && sj > bestv) { bestv = sj; bt = j; }
    }
    if (i == 0) {
        best_score[b] = bestv;
        best_tag[b]   = bt;
    }
}

// ---------------------------------------------------------------------------
// Backtrace: tags[t-1] = bptr[t][tags[t]]  (bptr stored [T][B]: coalesced)
// ---------------------------------------------------------------------------
__global__ __launch_bounds__(128) void backtrack(
    const unsigned int* __restrict__ bptrw,
    const int* __restrict__ best_tag,
    float* __restrict__ out_tags)   // d_out + 128, [B,T]
{
    const int b = threadIdx.x;
    if (b >= Bb) return;
    const long fb = (long)b * Tt;
    int tag = best_tag[b];
    out_tags[fb + Tt - 1] = (float)tag;
    #pragma unroll 8
    for (int t = Tt - 1; t >= 1; --t) {
        unsigned w = bptrw[(long)t * Bb + b];
        tag = (w >> (3 * tag)) & 7;
        out_tags[fb + t - 1] = (float)tag;
    }
}

// ---------------------------------------------------------------------------
extern "C" void kernel_launch(void* const* d_in, const int* in_sizes, int n_in,
                              void* d_out, int out_size, void* d_ws, size_t ws_size,
                              hipStream_t stream)
{
    const int*   sent    = (const int*)  d_in[0];
    const float* mask    = (const float*)d_in[1];
    const float* emb     = (const float*)d_in[2];
    const float* h0      = (const float*)d_in[3];
    const float* c0      = (const float*)d_in[4];
    const float* w_ih_l0 = (const float*)d_in[5];
    const float* w_hh_l0 = (const float*)d_in[6];
    const float* b_l0    = (const float*)d_in[7];
    const float* w_ih_l1 = (const float*)d_in[8];
    const float* w_hh_l1 = (const float*)d_in[9];
    const float* b_l1    = (const float*)d_in[10];
    const float* w_ih_l2 = (const float*)d_in[11];
    const float* w_hh_l2 = (const float*)d_in[12];
    const float* b_l2    = (const float*)d_in[13];
    const float* w_tag   = (const float*)d_in[14];
    const float* b_tag   = (const float*)d_in[15];
    const float* trans   = (const float*)d_in[16];

    float* out = (float*)d_out;

    char* ws = (char*)d_ws;
    const long xg_bytes = (long)Mrows * Ncols * 4;        // 104,857,600
    const long xa_bytes = (long)Mrows * 100 * 4;          //  26,214,400
    float*    xg    = (float*)(ws);
    float*    xa    = (float*)(ws + xg_bytes);
    float*    xb    = (float*)(ws + xg_bytes + xa_bytes);
    float*    feats = (float*)(ws + xg_bytes + 2 * xa_bytes);
    unsigned* bptrw = (unsigned*)(ws + xg_bytes + 2 * xa_bytes + (long)Mrows * 8 * 4);
    int*      btag  = (int*)(ws + xg_bytes + 2 * xa_bytes + (long)Mrows * 8 * 4 + (long)Bb * Tt * 4);

    dim3 gridG(Mrows / 64, (Ncols + 63) / 64);

    // layer 0 (embedding gathered inside the GEMM)
    gemm_xg<true><<<gridG, 256, 0, stream>>>(emb, sent, w_ih_l0, b_l0, xg, Mrows, Ncols, 300);
    lstm_scan<<<256, 64, 0, stream>>>(xg, w_hh_l0, h0 + 0 * Bb * Hh, c0 + 0 * Bb * Hh, xa);

    // layer 1
    gemm_xg<false><<<gridG, 256, 0, stream>>>(xa, nullptr, w_ih_l1, b_l1, xg, Mrows, Ncols, 100);
    lstm_scan<<<256, 64, 0, stream>>>(xg, w_hh_l1, h0 + 2 * Bb * Hh, c0 + 2 * Bb * Hh, xb);

    // layer 2
    gemm_xg<false><<<gridG, 256, 0, stream>>>(xb, nullptr, w_ih_l2, b_l2, xg, Mrows, Ncols, 100);
    lstm_scan<<<256, 64, 0, stream>>>(xg, w_hh_l2, h0 + 4 * Bb * Hh, c0 + 4 * Bb * Hh, xa);

    // tag projection + viterbi + backtrace
    feats_kernel<<<Mrows * 8 / 256, 256, 0, stream>>>(xa, w_tag, b_tag, mask, feats);
    viterbi_fwd<<<Bb / 8, 64, 0, stream>>>(feats, trans, bptrw, out, btag);
    backtrack<<<1, 128, 0, stream>>>(bptrw, btag, out + Bb);
}

// Round 10
// 1345.247 us; speedup vs baseline: 1.4894x; 1.4894x over previous
//
#include <hip/hip_runtime.h>

#define NEGV (-10000.0f)

static constexpr int Bb    = 128;
static constexpr int Tt    = 512;
static constexpr int Mrows = Bb * Tt;   // 65536
static constexpr int Hh    = 50;
static constexpr int START = 5;

typedef __attribute__((ext_vector_type(8))) short bf16x8;
typedef __attribute__((ext_vector_type(4))) float f32x4;

__device__ __forceinline__ float fsig(float x) {
    return __builtin_amdgcn_rcpf(1.0f + __expf(-x));
}
__device__ __forceinline__ float ftanh(float x) {
    return 2.0f * __builtin_amdgcn_rcpf(1.0f + __expf(-2.0f * x)) - 1.0f;
}
__device__ __forceinline__ unsigned short f2bf(float f) {
    unsigned u = __float_as_uint(f);
    u = (u + 0x7fffu + ((u >> 16) & 1u)) >> 16;   // RNE
    return (unsigned short)u;
}
#define BF(u) __uint_as_float(((unsigned)(u)) << 16)

// ---------------------------------------------------------------------------
// Convert W [400][K] fp32 -> [448][KP] bf16 (zero-padded rows/cols)
// ---------------------------------------------------------------------------
__global__ __launch_bounds__(256) void conv_w(
    const float* __restrict__ src, unsigned short* __restrict__ dst,
    int K, int KP)
{
    int gid = blockIdx.x * 256 + threadIdx.x;
    int tot = 448 * KP;
    if (gid >= tot) return;
    int r = gid / KP, c = gid % KP;
    float v = (r < 400 && c < K) ? src[r * K + c] : 0.f;
    dst[gid] = f2bf(v);
}

// ---------------------------------------------------------------------------
// Convert A rows (optionally gathered) fp32 -> [M][KP] bf16, 8 cols/thread
// ---------------------------------------------------------------------------
template <bool GATHER>
__global__ __launch_bounds__(256) void conv_a(
    const float* __restrict__ src, const int* __restrict__ idx,
    unsigned short* __restrict__ dst, int K, int KP, int cpr)
{
    long gid = (long)blockIdx.x * 256 + threadIdx.x;
    long tot = (long)Mrows * cpr;
    if (gid >= tot) return;
    long m = gid / cpr;
    int p = (int)(gid - m * cpr) * 8;
    const float* s = src + (GATHER ? (long)idx[m] : m) * K;
    unsigned u0, u1, u2, u3;
    {
        float x0 = (p + 0 < K) ? s[p + 0] : 0.f;
        float x1 = (p + 1 < K) ? s[p + 1] : 0.f;
        float x2 = (p + 2 < K) ? s[p + 2] : 0.f;
        float x3 = (p + 3 < K) ? s[p + 3] : 0.f;
        float x4 = (p + 4 < K) ? s[p + 4] : 0.f;
        float x5 = (p + 5 < K) ? s[p + 5] : 0.f;
        float x6 = (p + 6 < K) ? s[p + 6] : 0.f;
        float x7 = (p + 7 < K) ? s[p + 7] : 0.f;
        u0 = (unsigned)f2bf(x0) | ((unsigned)f2bf(x1) << 16);
        u1 = (unsigned)f2bf(x2) | ((unsigned)f2bf(x3) << 16);
        u2 = (unsigned)f2bf(x4) | ((unsigned)f2bf(x5) << 16);
        u3 = (unsigned)f2bf(x6) | ((unsigned)f2bf(x7) << 16);
    }
    uint4 v = make_uint4(u0, u1, u2, u3);
    *(uint4*)(dst + m * KP + p) = v;
}

// ---------------------------------------------------------------------------
// bf16 MFMA GEMM: C[M,400]bf16 = A[M,KP]bf16 @ W[448,KP]bf16^T + bias
// 128x64 tile, 4 waves (2x2), per wave 4x2 frags of 16x16, K-step 32.
// Fragment layout (guide m89/m97 gemm_bt): lane l reads 8 consecutive K
// at row (l&15), k-off (l>>4)*8 for BOTH operands; D: col=l&15,
// row=(l>>4)*4+reg.
// ---------------------------------------------------------------------------
__global__ __launch_bounds__(256) void gemm_mfma(
    const unsigned short* __restrict__ Ab,   // [M][KP]
    const unsigned short* __restrict__ Wb,   // [448][KP]
    const float* __restrict__ bias,          // [400]
    unsigned short* __restrict__ C,          // [M][400] bf16
    int KP)
{
    __shared__ unsigned short As[128][40];   // +8 pad: 80B row stride
    __shared__ unsigned short Ws[64][40];

    const int tid = threadIdx.x;
    const int m0 = blockIdx.x * 128;
    const int n0 = blockIdx.y * 64;

    const int w  = tid >> 6, l = tid & 63;
    const int wm = (w >> 1) * 64;        // wave m-offset in tile
    const int wn = (w & 1) * 32;         // wave n-offset in tile
    const int lr = l & 15;
    const int lk = (l >> 4) * 8;

    f32x4 acc[4][2] = {};

    for (int k0 = 0; k0 < KP; k0 += 32) {
        __syncthreads();   // protect LDS from previous iter's readers
        {
            // A tile: 512 16B-chunks; thread does chunk tid and tid+256
            int c = tid;
            int r = c >> 2, p = (c & 3) * 8;
            *(bf16x8*)&As[r][p] = *(const bf16x8*)(Ab + (long)(m0 + r) * KP + k0 + p);
            c = tid + 256;
            r = c >> 2; p = (c & 3) * 8;
            *(bf16x8*)&As[r][p] = *(const bf16x8*)(Ab + (long)(m0 + r) * KP + k0 + p);
            // W tile: 256 chunks
            r = tid >> 2; p = (tid & 3) * 8;
            *(bf16x8*)&Ws[r][p] = *(const bf16x8*)(Wb + (long)(n0 + r) * KP + k0 + p);
        }
        __syncthreads();

        bf16x8 af0 = *(const bf16x8*)&As[wm +  0 + lr][lk];
        bf16x8 af1 = *(const bf16x8*)&As[wm + 16 + lr][lk];
        bf16x8 af2 = *(const bf16x8*)&As[wm + 32 + lr][lk];
        bf16x8 af3 = *(const bf16x8*)&As[wm + 48 + lr][lk];
        bf16x8 wf0 = *(const bf16x8*)&Ws[wn +  0 + lr][lk];
        bf16x8 wf1 = *(const bf16x8*)&Ws[wn + 16 + lr][lk];

        acc[0][0] = __builtin_amdgcn_mfma_f32_16x16x32_bf16(af0, wf0, acc[0][0], 0, 0, 0);
        acc[0][1] = __builtin_amdgcn_mfma_f32_16x16x32_bf16(af0, wf1, acc[0][1], 0, 0, 0);
        acc[1][0] = __builtin_amdgcn_mfma_f32_16x16x32_bf16(af1, wf0, acc[1][0], 0, 0, 0);
        acc[1][1] = __builtin_amdgcn_mfma_f32_16x16x32_bf16(af1, wf1, acc[1][1], 0, 0, 0);
        acc[2][0] = __builtin_amdgcn_mfma_f32_16x16x32_bf16(af2, wf0, acc[2][0], 0, 0, 0);
        acc[2][1] = __builtin_amdgcn_mfma_f32_16x16x32_bf16(af2, wf1, acc[2][1], 0, 0, 0);
        acc[3][0] = __builtin_amdgcn_mfma_f32_16x16x32_bf16(af3, wf0, acc[3][0], 0, 0, 0);
        acc[3][1] = __builtin_amdgcn_mfma_f32_16x16x32_bf16(af3, wf1, acc[3][1], 0, 0, 0);
    }

    // epilogue: D row=(l>>4)*4+i, col=l&15 within each 16x16 frag
    const int orow = (l >> 4) * 4;
    const int ocol = l & 15;
    #pragma unroll
    for (int a = 0; a < 4; ++a) {
        #pragma unroll
        for (int bb = 0; bb < 2; ++bb) {
            const int col = n0 + wn + bb * 16 + ocol;
            if (col < 400) {
                const float bv = bias[col];
                #pragma unroll
                for (int i = 0; i < 4; ++i) {
                    const long row = m0 + wm + a * 16 + orow + i;
                    C[row * 400 + col] = f2bf(acc[a][bb][i] + bv);
                }
            }
        }
    }
}

// ---------------------------------------------------------------------------
// LSTM scan (r8 structure, proven 319us): 4 waves per (b,dir), gate-major,
// 50 named laundered scalar weights/thread, one raw s_barrier per step
// (lgkm-only drain). ONLY change: xg is now bf16 (ushort loads + cvt).
// ---------------------------------------------------------------------------
__global__ void
__attribute__((amdgpu_flat_work_group_size(256, 256), amdgpu_waves_per_eu(1, 1)))
lstm_scan(
    const unsigned short* __restrict__ xg,  // [M,400] bf16 (bias added)
    const float* __restrict__ w_hh,         // [2,200,50]
    const float* __restrict__ h0,           // layer base: [2,B,50]
    const float* __restrict__ c0,
    float* __restrict__ xout)               // [M,100] fp32
{
    const int b    = blockIdx.x & 127;
    const int dir  = blockIdx.x >> 7;
    const int tid  = threadIdx.x;
    const int lane = tid & 63;
    const int wv   = tid >> 6;

    __shared__ __align__(16) float hsw[4][56];
    __shared__ float pre[2][200];

    const int gr = (tid < 200) ? tid : 199;

    const float* wr = w_hh + ((long)dir * 200 + gr) * 50;
    float w0  = wr[0],  w1  = wr[1],  w2  = wr[2],  w3  = wr[3],  w4  = wr[4];
    float w5  = wr[5],  w6  = wr[6],  w7  = wr[7],  w8  = wr[8],  w9  = wr[9];
    float w10 = wr[10], w11 = wr[11], w12 = wr[12], w13 = wr[13], w14 = wr[14];
    float w15 = wr[15], w16 = wr[16], w17 = wr[17], w18 = wr[18], w19 = wr[19];
    float w20 = wr[20], w21 = wr[21], w22 = wr[22], w23 = wr[23], w24 = wr[24];
    float w25 = wr[25], w26 = wr[26], w27 = wr[27], w28 = wr[28], w29 = wr[29];
    float w30 = wr[30], w31 = wr[31], w32 = wr[32], w33 = wr[33], w34 = wr[34];
    float w35 = wr[35], w36 = wr[36], w37 = wr[37], w38 = wr[38], w39 = wr[39];
    float w40 = wr[40], w41 = wr[41], w42 = wr[42], w43 = wr[43], w44 = wr[44];
    float w45 = wr[45], w46 = wr[46], w47 = wr[47], w48 = wr[48], w49 = wr[49];
    asm volatile("" : "+v"(w0), "+v"(w1), "+v"(w2), "+v"(w3), "+v"(w4),
                      "+v"(w5), "+v"(w6), "+v"(w7), "+v"(w8), "+v"(w9));
    asm volatile("" : "+v"(w10), "+v"(w11), "+v"(w12), "+v"(w13), "+v"(w14),
                      "+v"(w15), "+v"(w16), "+v"(w17), "+v"(w18), "+v"(w19));
    asm volatile("" : "+v"(w20), "+v"(w21), "+v"(w22), "+v"(w23), "+v"(w24),
                      "+v"(w25), "+v"(w26), "+v"(w27), "+v"(w28), "+v"(w29));
    asm volatile("" : "+v"(w30), "+v"(w31), "+v"(w32), "+v"(w33), "+v"(w34),
                      "+v"(w35), "+v"(w36), "+v"(w37), "+v"(w38), "+v"(w39));
    asm volatile("" : "+v"(w40), "+v"(w41), "+v"(w42), "+v"(w43), "+v"(w44),
                      "+v"(w45), "+v"(w46), "+v"(w47), "+v"(w48), "+v"(w49));

    float* hm = &hsw[wv][0];
    const float4* h4 = (const float4*)hm;
    float c = 0.f;
    if (lane < 50) {
        c        = c0[((long)dir * Bb + b) * Hh + lane];
        hm[lane] = h0[((long)dir * Bb + b) * Hh + lane];
    } else if (lane < 56) {
        hm[lane] = 0.f;
    }
    __syncthreads();

    const long rowbase = (long)b * Tt;
    const unsigned short* xbase = xg + rowbase * 400 + dir * 200 + gr;
    float* op = xout + rowbase * 100 + dir * 50 + lane;

    #define XLD(s)  xbase[(long)(dir ? (Tt - 1 - (s)) : (s)) * 400]
    #define TTOF(s) (dir ? (Tt - 1 - (s)) : (s))

    #define G4(Q, WA, WB, WC, WD) \
        hv = h4[Q]; s0 += (WA) * hv.x; s1 += (WB) * hv.y; \
                    s2 += (WC) * hv.z; s3 += (WD) * hv.w;

    #define STEP(PRE, XIN, TT) do {                                         \
        if (tid < 200) {                                                    \
            float s0 = BF(XIN), s1 = 0.f, s2 = 0.f, s3 = 0.f;               \
            float4 hv;                                                      \
            G4(0,  w0,  w1,  w2,  w3)                                       \
            G4(1,  w4,  w5,  w6,  w7)                                       \
            G4(2,  w8,  w9,  w10, w11)                                      \
            G4(3,  w12, w13, w14, w15)                                      \
            G4(4,  w16, w17, w18, w19)                                      \
            G4(5,  w20, w21, w22, w23)                                      \
            G4(6,  w24, w25, w26, w27)                                      \
            G4(7,  w28, w29, w30, w31)                                      \
            G4(8,  w32, w33, w34, w35)                                      \
            G4(9,  w36, w37, w38, w39)                                      \
            G4(10, w40, w41, w42, w43)                                      \
            G4(11, w44, w45, w46, w47)                                      \
            { hv = h4[12]; s0 += w48 * hv.x; s1 += w49 * hv.y; }            \
            (PRE)[tid] = (s0 + s1) + (s2 + s3);                             \
        }                                                                   \
        asm volatile("s_waitcnt lgkmcnt(0)\n\ts_barrier" ::: "memory");     \
        if (lane < 50) {                                                    \
            const float gi = fsig((PRE)[lane]);                             \
            const float gf = fsig((PRE)[50 + lane]);                        \
            const float gc = ftanh((PRE)[100 + lane]);                      \
            const float go = fsig((PRE)[150 + lane]);                       \
            c = gf * c + gi * gc;                                           \
            const float h = go * ftanh(c);                                  \
            hm[lane] = h;                                                   \
            if (wv == 0) op[(long)(TT) * 100] = h;                          \
        }                                                                   \
    } while (0)

    unsigned xc0 = XLD(0), xc1 = XLD(1), xc2 = XLD(2), xc3 = XLD(3);
    unsigned xn0 = 0, xn1 = 0, xn2 = 0, xn3 = 0;

    for (int blk = 0; blk < Tt / 4; ++blk) {
        const int s0i = blk * 4;
        if (blk < Tt / 4 - 1) {
            xn0 = XLD(s0i + 4); xn1 = XLD(s0i + 5);
            xn2 = XLD(s0i + 6); xn3 = XLD(s0i + 7);
        }
        STEP(pre[0], xc0, TTOF(s0i + 0));
        STEP(pre[1], xc1, TTOF(s0i + 1));
        STEP(pre[0], xc2, TTOF(s0i + 2));
        STEP(pre[1], xc3, TTOF(s0i + 3));
        xc0 = xn0; xc1 = xn1; xc2 = xn2; xc3 = xn3;
    }
    #undef STEP
    #undef G4
    #undef XLD
    #undef TTOF
}

// ---------------------------------------------------------------------------
// feats[row, i] = (x[row,:] . w_tag[i,:] + b_tag[i]) * mask[row], padded to 8
// ---------------------------------------------------------------------------
__global__ __launch_bounds__(256) void feats_kernel(
    const float* __restrict__ x,      // [M,100] fp32
    const float* __restrict__ w_tag,  // [7,100]
    const float* __restrict__ b_tag,  // [7]
    const float* __restrict__ mask,   // [M]
    float* __restrict__ feats)        // [M,8]
{
    const int gid = blockIdx.x * 256 + threadIdx.x;
    const int row = gid >> 3;
    const int i   = gid & 7;
    if (row >= Mrows) return;
    if (i == 7) { feats[(long)row * 8 + 7] = 0.f; return; }
    const float4* xr = (const float4*)(x + (long)row * 100);
    const float4* wr = (const float4*)(w_tag + (long)i * 100);
    float acc = b_tag[i];
    #pragma unroll
    for (int q = 0; q < 25; ++q) {
        float4 a = xr[q];
        float4 b = wr[q];
        acc += a.x * b.x + a.y * b.y + a.z * b.z + a.w * b.w;
    }
    feats[(long)row * 8 + i] = acc * mask[row];
}

// ---------------------------------------------------------------------------
// Viterbi forward. 8 lanes per batch row; backpointers packed [T][B].
// ---------------------------------------------------------------------------
__global__ __launch_bounds__(64) void viterbi_fwd(
    const float* __restrict__ feats,   // [M,8]
    const float* __restrict__ trans,   // [7,7]
    unsigned int* __restrict__ bptrw,  // [T*B]
    float* __restrict__ best_score,    // [B] -> d_out
    int* __restrict__ best_tag)        // [B] -> ws
{
    const int lane = threadIdx.x;
    const int sub  = lane >> 3;
    const int i    = lane & 7;
    const int b    = blockIdx.x * 8 + sub;
    const int base = lane & 56;

    float tr[7];
    #pragma unroll
    for (int j = 0; j < 7; ++j) tr[j] = (i < 7) ? trans[i * 7 + j] : -1e30f;

    float score = (i == START) ? 0.0f : NEGV;
    const long fb = (long)b * Tt;

    float featc = feats[(fb + 0) * 8 + i];
    for (int t = 0; t < Tt; ++t) {
        float featn = (t + 1 < Tt) ? feats[(fb + t + 1) * 8 + i] : 0.f;
        float best = -3.4e38f;
        int bp = 0;
        #pragma unroll
        for (int j = 0; j < 7; ++j) {
            float sj = __shfl(score, base | j, 64);
            float m = sj + tr[j];
            if (m > best) { best = m; bp = j; }
        }
        if (i < 7) score = best + featc;
        unsigned v = (i < 7) ? ((unsigned)bp << (3 * i)) : 0u;
        v |= __shfl_xor(v, 1, 64);
        v |= __shfl_xor(v, 2, 64);
        v |= __shfl_xor(v, 4, 64);
        if (i == 0) bptrw[(long)t * Bb + b] = v;
        featc = featn;
    }

    float bestv = score;
    int bt = 0;
    #pragma unroll
    for (int j = 1; j < 7; ++j) {
        float sj = __shfl(score, base | j, 64);
        if (i == 0 && sj > bestv) { bestv = sj; bt = j; }
    }
    if (i == 0) {
        best_score[b] = bestv;
        best_tag[b]   = bt;
    }
}

// ---------------------------------------------------------------------------
__global__ __launch_bounds__(128) void backtrack(
    const unsigned int* __restrict__ bptrw,
    const int* __restrict__ best_tag,
    float* __restrict__ out_tags)   // d_out + 128, [B,T]
{
    const int b = threadIdx.x;
    if (b >= Bb) return;
    const long fb = (long)b * Tt;
    int tag = best_tag[b];
    out_tags[fb + Tt - 1] = (float)tag;
    #pragma unroll 8
    for (int t = Tt - 1; t >= 1; --t) {
        unsigned w = bptrw[(long)t * Bb + b];
        tag = (w >> (3 * tag)) & 7;
        out_tags[fb + t - 1] = (float)tag;
    }
}

// ---------------------------------------------------------------------------
extern "C" void kernel_launch(void* const* d_in, const int* in_sizes, int n_in,
                              void* d_out, int out_size, void* d_ws, size_t ws_size,
                              hipStream_t stream)
{
    const int*   sent    = (const int*)  d_in[0];
    const float* mask    = (const float*)d_in[1];
    const float* emb     = (const float*)d_in[2];
    const float* h0      = (const float*)d_in[3];
    const float* c0      = (const float*)d_in[4];
    const float* w_ih_l0 = (const float*)d_in[5];
    const float* w_hh_l0 = (const float*)d_in[6];
    const float* b_l0    = (const float*)d_in[7];
    const float* w_ih_l1 = (const float*)d_in[8];
    const float* w_hh_l1 = (const float*)d_in[9];
    const float* b_l1    = (const float*)d_in[10];
    const float* w_ih_l2 = (const float*)d_in[11];
    const float* w_hh_l2 = (const float*)d_in[12];
    const float* b_l2    = (const float*)d_in[13];
    const float* w_tag   = (const float*)d_in[14];
    const float* b_tag   = (const float*)d_in[15];
    const float* trans   = (const float*)d_in[16];

    float* out = (float*)d_out;
    char* ws = (char*)d_ws;

    // workspace layout (bytes)
    unsigned short* xg    = (unsigned short*)(ws);                    // 52,428,800
    float*          xa    = (float*)(ws + 52428800L);                 // 26,214,400
    float*          xb    = (float*)(ws + 78643200L);                 // 26,214,400
    unsigned short* AbR   = (unsigned short*)(ws + 104857600L);       // 41,943,040
    float*          feats = (float*)(ws + 146800640L);                //  2,097,152
    unsigned*       bptrw = (unsigned*)(ws + 148897792L);             //    262,144
    unsigned short* Wb0   = (unsigned short*)(ws + 149159936L);       //    286,720
    unsigned short* Wb1   = (unsigned short*)(ws + 149446656L);       //    114,688
    unsigned short* Wb2   = (unsigned short*)(ws + 149561344L);       //    114,688
    int*            btag  = (int*)(ws + 149676032L);                  //        512

    dim3 gridG(Mrows / 128, 7);   // 128x64 tiles over [65536, 448]

    // weight conversions (independent)
    conv_w<<<(448 * 320 + 255) / 256, 256, 0, stream>>>(w_ih_l0, Wb0, 300, 320);
    conv_w<<<(448 * 128 + 255) / 256, 256, 0, stream>>>(w_ih_l1, Wb1, 100, 128);
    conv_w<<<(448 * 128 + 255) / 256, 256, 0, stream>>>(w_ih_l2, Wb2, 100, 128);

    // layer 0
    conv_a<true><<<(Mrows * 40 + 255) / 256, 256, 0, stream>>>(emb, sent, AbR, 300, 320, 40);
    gemm_mfma<<<gridG, 256, 0, stream>>>(AbR, Wb0, b_l0, xg, 320);
    lstm_scan<<<256, 256, 0, stream>>>(xg, w_hh_l0, h0 + 0 * Bb * Hh, c0 + 0 * Bb * Hh, xa);

    // layer 1
    conv_a<false><<<(Mrows * 16 + 255) / 256, 256, 0, stream>>>(xa, nullptr, AbR, 100, 128, 16);
    gemm_mfma<<<gridG, 256, 0, stream>>>(AbR, Wb1, b_l1, xg, 128);
    lstm_scan<<<256, 256, 0, stream>>>(xg, w_hh_l1, h0 + 2 * Bb * Hh, c0 + 2 * Bb * Hh, xb);

    // layer 2
    conv_a<false><<<(Mrows * 16 + 255) / 256, 256, 0, stream>>>(xb, nullptr, AbR, 100, 128, 16);
    gemm_mfma<<<gridG, 256, 0, stream>>>(AbR, Wb2, b_l2, xg, 128);
    lstm_scan<<<256, 256, 0, stream>>>(xg, w_hh_l2, h0 + 4 * Bb * Hh, c0 + 4 * Bb * Hh, xa);

    // tag projection + viterbi + backtrace
    feats_kernel<<<Mrows * 8 / 256, 256, 0, stream>>>(xa, w_tag, b_tag, mask, feats);
    viterbi_fwd<<<Bb / 8, 64, 0, stream>>>(feats, trans, bptrw, out, btag);
    backtrack<<<1, 128, 0, stream>>>(bptrw, btag, out + Bb);
}

// Round 11
// 1191.600 us; speedup vs baseline: 1.6815x; 1.1289x over previous
//
#include <hip/hip_runtime.h>

#define NEGV (-10000.0f)

static constexpr int Bb    = 128;
static constexpr int Tt    = 512;
static constexpr int Mrows = Bb * Tt;   // 65536
static constexpr int Hh    = 50;
static constexpr int START = 5;

typedef __attribute__((ext_vector_type(8))) short bf16x8;
typedef __attribute__((ext_vector_type(4))) float f32x4;

__device__ __forceinline__ float fsig(float x) {
    return __builtin_amdgcn_rcpf(1.0f + __expf(-x));
}
__device__ __forceinline__ float ftanh(float x) {
    return 2.0f * __builtin_amdgcn_rcpf(1.0f + __expf(-2.0f * x)) - 1.0f;
}
__device__ __forceinline__ unsigned short f2bf(float f) {
    unsigned u = __float_as_uint(f);
    u = (u + 0x7fffu + ((u >> 16) & 1u)) >> 16;   // RNE
    return (unsigned short)u;
}
#define BF(u) __uint_as_float(((unsigned)(u)) << 16)

// ---------------------------------------------------------------------------
// Convert W [400][K] fp32 -> [448][KP] bf16 (zero-padded rows/cols)
// ---------------------------------------------------------------------------
__global__ __launch_bounds__(256) void conv_w(
    const float* __restrict__ src, unsigned short* __restrict__ dst,
    int K, int KP)
{
    int gid = blockIdx.x * 256 + threadIdx.x;
    int tot = 448 * KP;
    if (gid >= tot) return;
    int r = gid / KP, c = gid % KP;
    float v = (r < 400 && c < K) ? src[r * K + c] : 0.f;
    dst[gid] = f2bf(v);
}

// ---------------------------------------------------------------------------
// Convert A rows (optionally gathered) fp32 -> [M][KP] bf16, 8 cols/thread
// ---------------------------------------------------------------------------
template <bool GATHER>
__global__ __launch_bounds__(256) void conv_a(
    const float* __restrict__ src, const int* __restrict__ idx,
    unsigned short* __restrict__ dst, int K, int KP, int cpr)
{
    long gid = (long)blockIdx.x * 256 + threadIdx.x;
    long tot = (long)Mrows * cpr;
    if (gid >= tot) return;
    long m = gid / cpr;
    int p = (int)(gid - m * cpr) * 8;
    const float* s = src + (GATHER ? (long)idx[m] : m) * K;
    unsigned u0, u1, u2, u3;
    {
        float x0 = (p + 0 < K) ? s[p + 0] : 0.f;
        float x1 = (p + 1 < K) ? s[p + 1] : 0.f;
        float x2 = (p + 2 < K) ? s[p + 2] : 0.f;
        float x3 = (p + 3 < K) ? s[p + 3] : 0.f;
        float x4 = (p + 4 < K) ? s[p + 4] : 0.f;
        float x5 = (p + 5 < K) ? s[p + 5] : 0.f;
        float x6 = (p + 6 < K) ? s[p + 6] : 0.f;
        float x7 = (p + 7 < K) ? s[p + 7] : 0.f;
        u0 = (unsigned)f2bf(x0) | ((unsigned)f2bf(x1) << 16);
        u1 = (unsigned)f2bf(x2) | ((unsigned)f2bf(x3) << 16);
        u2 = (unsigned)f2bf(x4) | ((unsigned)f2bf(x5) << 16);
        u3 = (unsigned)f2bf(x6) | ((unsigned)f2bf(x7) << 16);
    }
    uint4 v = make_uint4(u0, u1, u2, u3);
    *(uint4*)(dst + m * KP + p) = v;
}

// ---------------------------------------------------------------------------
// bf16 MFMA GEMM: C[M,400]bf16 = A[M,KP]bf16 @ W[448,KP]bf16^T + bias
// (unchanged from r10, verified absmax 2.0)
// ---------------------------------------------------------------------------
__global__ __launch_bounds__(256) void gemm_mfma(
    const unsigned short* __restrict__ Ab,   // [M][KP]
    const unsigned short* __restrict__ Wb,   // [448][KP]
    const float* __restrict__ bias,          // [400]
    unsigned short* __restrict__ C,          // [M][400] bf16
    int KP)
{
    __shared__ unsigned short As[128][40];   // +8 pad: 80B row stride
    __shared__ unsigned short Ws[64][40];

    const int tid = threadIdx.x;
    const int m0 = blockIdx.x * 128;
    const int n0 = blockIdx.y * 64;

    const int w  = tid >> 6, l = tid & 63;
    const int wm = (w >> 1) * 64;
    const int wn = (w & 1) * 32;
    const int lr = l & 15;
    const int lk = (l >> 4) * 8;

    f32x4 acc[4][2] = {};

    for (int k0 = 0; k0 < KP; k0 += 32) {
        __syncthreads();
        {
            int c = tid;
            int r = c >> 2, p = (c & 3) * 8;
            *(bf16x8*)&As[r][p] = *(const bf16x8*)(Ab + (long)(m0 + r) * KP + k0 + p);
            c = tid + 256;
            r = c >> 2; p = (c & 3) * 8;
            *(bf16x8*)&As[r][p] = *(const bf16x8*)(Ab + (long)(m0 + r) * KP + k0 + p);
            r = tid >> 2; p = (tid & 3) * 8;
            *(bf16x8*)&Ws[r][p] = *(const bf16x8*)(Wb + (long)(n0 + r) * KP + k0 + p);
        }
        __syncthreads();

        bf16x8 af0 = *(const bf16x8*)&As[wm +  0 + lr][lk];
        bf16x8 af1 = *(const bf16x8*)&As[wm + 16 + lr][lk];
        bf16x8 af2 = *(const bf16x8*)&As[wm + 32 + lr][lk];
        bf16x8 af3 = *(const bf16x8*)&As[wm + 48 + lr][lk];
        bf16x8 wf0 = *(const bf16x8*)&Ws[wn +  0 + lr][lk];
        bf16x8 wf1 = *(const bf16x8*)&Ws[wn + 16 + lr][lk];

        acc[0][0] = __builtin_amdgcn_mfma_f32_16x16x32_bf16(af0, wf0, acc[0][0], 0, 0, 0);
        acc[0][1] = __builtin_amdgcn_mfma_f32_16x16x32_bf16(af0, wf1, acc[0][1], 0, 0, 0);
        acc[1][0] = __builtin_amdgcn_mfma_f32_16x16x32_bf16(af1, wf0, acc[1][0], 0, 0, 0);
        acc[1][1] = __builtin_amdgcn_mfma_f32_16x16x32_bf16(af1, wf1, acc[1][1], 0, 0, 0);
        acc[2][0] = __builtin_amdgcn_mfma_f32_16x16x32_bf16(af2, wf0, acc[2][0], 0, 0, 0);
        acc[2][1] = __builtin_amdgcn_mfma_f32_16x16x32_bf16(af2, wf1, acc[2][1], 0, 0, 0);
        acc[3][0] = __builtin_amdgcn_mfma_f32_16x16x32_bf16(af3, wf0, acc[3][0], 0, 0, 0);
        acc[3][1] = __builtin_amdgcn_mfma_f32_16x16x32_bf16(af3, wf1, acc[3][1], 0, 0, 0);
    }

    const int orow = (l >> 4) * 4;
    const int ocol = l & 15;
    #pragma unroll
    for (int a = 0; a < 4; ++a) {
        #pragma unroll
        for (int bb = 0; bb < 2; ++bb) {
            const int col = n0 + wn + bb * 16 + ocol;
            if (col < 400) {
                const float bv = bias[col];
                #pragma unroll
                for (int i = 0; i < 4; ++i) {
                    const long row = m0 + wm + a * 16 + orow + i;
                    C[row * 400 + col] = f2bf(acc[a][bb][i] + bv);
                }
            }
        }
    }
}

// ---------------------------------------------------------------------------
// LSTM scan: r8 skeleton (4 waves, gate-major, 50 laundered reg weights,
// one raw s_barrier/step) BUT the h broadcast now uses v_readlane instead
// of LDS: every wave computes all 50 h redundantly in lanes 0-49, so
// h[j] = readlane(hreg, j) in-wave. This deletes 52 ds_read_b128/step
// (the ~624cy shared-DS-pipe floor diagnosed from r4==r8 invariance).
// Remaining DS/step: pre[] write + 4 reads per wave (~20 b32 ops).
// ---------------------------------------------------------------------------
#define H(J) __uint_as_float((unsigned)__builtin_amdgcn_readlane((int)__float_as_uint(hreg), (J)))

__global__ void
__attribute__((amdgpu_flat_work_group_size(256, 256), amdgpu_waves_per_eu(1, 1)))
lstm_scan(
    const unsigned short* __restrict__ xg,  // [M,400] bf16 (bias added)
    const float* __restrict__ w_hh,         // [2,200,50]
    const float* __restrict__ h0,           // layer base: [2,B,50]
    const float* __restrict__ c0,
    float* __restrict__ xout)               // [M,100] fp32
{
    const int b    = blockIdx.x & 127;
    const int dir  = blockIdx.x >> 7;
    const int tid  = threadIdx.x;
    const int lane = tid & 63;
    const int wv   = tid >> 6;

    __shared__ float pre[2][200];   // double-buffered pre-gates (only LDS)

    const int gr = (tid < 200) ? tid : 199;

    const float* wr = w_hh + ((long)dir * 200 + gr) * 50;
    float w0  = wr[0],  w1  = wr[1],  w2  = wr[2],  w3  = wr[3],  w4  = wr[4];
    float w5  = wr[5],  w6  = wr[6],  w7  = wr[7],  w8  = wr[8],  w9  = wr[9];
    float w10 = wr[10], w11 = wr[11], w12 = wr[12], w13 = wr[13], w14 = wr[14];
    float w15 = wr[15], w16 = wr[16], w17 = wr[17], w18 = wr[18], w19 = wr[19];
    float w20 = wr[20], w21 = wr[21], w22 = wr[22], w23 = wr[23], w24 = wr[24];
    float w25 = wr[25], w26 = wr[26], w27 = wr[27], w28 = wr[28], w29 = wr[29];
    float w30 = wr[30], w31 = wr[31], w32 = wr[32], w33 = wr[33], w34 = wr[34];
    float w35 = wr[35], w36 = wr[36], w37 = wr[37], w38 = wr[38], w39 = wr[39];
    float w40 = wr[40], w41 = wr[41], w42 = wr[42], w43 = wr[43], w44 = wr[44];
    float w45 = wr[45], w46 = wr[46], w47 = wr[47], w48 = wr[48], w49 = wr[49];
    asm volatile("" : "+v"(w0), "+v"(w1), "+v"(w2), "+v"(w3), "+v"(w4),
                      "+v"(w5), "+v"(w6), "+v"(w7), "+v"(w8), "+v"(w9));
    asm volatile("" : "+v"(w10), "+v"(w11), "+v"(w12), "+v"(w13), "+v"(w14),
                      "+v"(w15), "+v"(w16), "+v"(w17), "+v"(w18), "+v"(w19));
    asm volatile("" : "+v"(w20), "+v"(w21), "+v"(w22), "+v"(w23), "+v"(w24),
                      "+v"(w25), "+v"(w26), "+v"(w27), "+v"(w28), "+v"(w29));
    asm volatile("" : "+v"(w30), "+v"(w31), "+v"(w32), "+v"(w33), "+v"(w34),
                      "+v"(w35), "+v"(w36), "+v"(w37), "+v"(w38), "+v"(w39));
    asm volatile("" : "+v"(w40), "+v"(w41), "+v"(w42), "+v"(w43), "+v"(w44),
                      "+v"(w45), "+v"(w46), "+v"(w47), "+v"(w48), "+v"(w49));

    // h and c live in registers of lanes 0-49 of EVERY wave (redundant).
    float hreg = 0.f, c = 0.f;
    if (lane < 50) {
        c    = c0[((long)dir * Bb + b) * Hh + lane];
        hreg = h0[((long)dir * Bb + b) * Hh + lane];
    }
    __syncthreads();

    const long rowbase = (long)b * Tt;
    const unsigned short* xbase = xg + rowbase * 400 + dir * 200 + gr;
    float* op = xout + rowbase * 100 + dir * 50 + lane;

    #define XLD(s)  xbase[(long)(dir ? (Tt - 1 - (s)) : (s)) * 400]
    #define TTOF(s) (dir ? (Tt - 1 - (s)) : (s))

    #define STEP(PRE, XIN, TT) do {                                         \
        if (tid < 200) {                                                    \
            float s0 = BF(XIN), s1 = 0.f, s2 = 0.f, s3 = 0.f;               \
            s0 += w0 *H(0);  s1 += w1 *H(1);  s2 += w2 *H(2);  s3 += w3 *H(3);  \
            s0 += w4 *H(4);  s1 += w5 *H(5);  s2 += w6 *H(6);  s3 += w7 *H(7);  \
            s0 += w8 *H(8);  s1 += w9 *H(9);  s2 += w10*H(10); s3 += w11*H(11); \
            s0 += w12*H(12); s1 += w13*H(13); s2 += w14*H(14); s3 += w15*H(15); \
            s0 += w16*H(16); s1 += w17*H(17); s2 += w18*H(18); s3 += w19*H(19); \
            s0 += w20*H(20); s1 += w21*H(21); s2 += w22*H(22); s3 += w23*H(23); \
            s0 += w24*H(24); s1 += w25*H(25); s2 += w26*H(26); s3 += w27*H(27); \
            s0 += w28*H(28); s1 += w29*H(29); s2 += w30*H(30); s3 += w31*H(31); \
            s0 += w32*H(32); s1 += w33*H(33); s2 += w34*H(34); s3 += w35*H(35); \
            s0 += w36*H(36); s1 += w37*H(37); s2 += w38*H(38); s3 += w39*H(39); \
            s0 += w40*H(40); s1 += w41*H(41); s2 += w42*H(42); s3 += w43*H(43); \
            s0 += w44*H(44); s1 += w45*H(45); s2 += w46*H(46); s3 += w47*H(47); \
            s0 += w48*H(48); s1 += w49*H(49);                               \
            (PRE)[tid] = (s0 + s1) + (s2 + s3);                             \
        }                                                                   \
        asm volatile("s_waitcnt lgkmcnt(0)\n\ts_barrier" ::: "memory");     \
        if (lane < 50) {                                                    \
            const float gi = fsig((PRE)[lane]);                             \
            const float gf = fsig((PRE)[50 + lane]);                        \
            const float gc = ftanh((PRE)[100 + lane]);                      \
            const float go = fsig((PRE)[150 + lane]);                       \
            c = gf * c + gi * gc;                                           \
            hreg = go * ftanh(c);                                           \
            if (wv == 0) op[(long)(TT) * 100] = hreg;                       \
        }                                                                   \
    } while (0)

    unsigned xc0 = XLD(0), xc1 = XLD(1), xc2 = XLD(2), xc3 = XLD(3);
    unsigned xn0 = 0, xn1 = 0, xn2 = 0, xn3 = 0;

    for (int blk = 0; blk < Tt / 4; ++blk) {
        const int s0i = blk * 4;
        if (blk < Tt / 4 - 1) {
            xn0 = XLD(s0i + 4); xn1 = XLD(s0i + 5);
            xn2 = XLD(s0i + 6); xn3 = XLD(s0i + 7);
        }
        STEP(pre[0], xc0, TTOF(s0i + 0));
        STEP(pre[1], xc1, TTOF(s0i + 1));
        STEP(pre[0], xc2, TTOF(s0i + 2));
        STEP(pre[1], xc3, TTOF(s0i + 3));
        xc0 = xn0; xc1 = xn1; xc2 = xn2; xc3 = xn3;
    }
    #undef STEP
    #undef XLD
    #undef TTOF
}

// ---------------------------------------------------------------------------
// feats[row, i] = (x[row,:] . w_tag[i,:] + b_tag[i]) * mask[row], padded to 8
// ---------------------------------------------------------------------------
__global__ __launch_bounds__(256) void feats_kernel(
    const float* __restrict__ x,      // [M,100] fp32
    const float* __restrict__ w_tag,  // [7,100]
    const float* __restrict__ b_tag,  // [7]
    const float* __restrict__ mask,   // [M]
    float* __restrict__ feats)        // [M,8]
{
    const int gid = blockIdx.x * 256 + threadIdx.x;
    const int row = gid >> 3;
    const int i   = gid & 7;
    if (row >= Mrows) return;
    if (i == 7) { feats[(long)row * 8 + 7] = 0.f; return; }
    const float4* xr = (const float4*)(x + (long)row * 100);
    const float4* wr = (const float4*)(w_tag + (long)i * 100);
    float acc = b_tag[i];
    #pragma unroll
    for (int q = 0; q < 25; ++q) {
        float4 a = xr[q];
        float4 b = wr[q];
        acc += a.x * b.x + a.y * b.y + a.z * b.z + a.w * b.w;
    }
    feats[(long)row * 8 + i] = acc * mask[row];
}

// ---------------------------------------------------------------------------
// Viterbi forward. 8 lanes per batch row; backpointers packed [T][B].
// ---------------------------------------------------------------------------
__global__ __launch_bounds__(64) void viterbi_fwd(
    const float* __restrict__ feats,   // [M,8]
    const float* __restrict__ trans,   // [7,7]
    unsigned int* __restrict__ bptrw,  // [T*B]
    float* __restrict__ best_score,    // [B] -> d_out
    int* __restrict__ best_tag)        // [B] -> ws
{
    const int lane = threadIdx.x;
    const int sub  = lane >> 3;
    const int i    = lane & 7;
    const int b    = blockIdx.x * 8 + sub;
    const int base = lane & 56;

    float tr[7];
    #pragma unroll
    for (int j = 0; j < 7; ++j) tr[j] = (i < 7) ? trans[i * 7 + j] : -1e30f;

    float score = (i == START) ? 0.0f : NEGV;
    const long fb = (long)b * Tt;

    float featc = feats[(fb + 0) * 8 + i];
    for (int t = 0; t < Tt; ++t) {
        float featn = (t + 1 < Tt) ? feats[(fb + t + 1) * 8 + i] : 0.f;
        float best = -3.4e38f;
        int bp = 0;
        #pragma unroll
        for (int j = 0; j < 7; ++j) {
            float sj = __shfl(score, base | j, 64);
            float m = sj + tr[j];
            if (m > best) { best = m; bp = j; }
        }
        if (i < 7) score = best + featc;
        unsigned v = (i < 7) ? ((unsigned)bp << (3 * i)) : 0u;
        v |= __shfl_xor(v, 1, 64);
        v |= __shfl_xor(v, 2, 64);
        v |= __shfl_xor(v, 4, 64);
        if (i == 0) bptrw[(long)t * Bb + b] = v;
        featc = featn;
    }

    float bestv = score;
    int bt = 0;
    #pragma unroll
    for (int j = 1; j < 7; ++j) {
        float sj = __shfl(score, base | j, 64);
        if (i == 0 && sj > bestv) { bestv = sj; bt = j; }
    }
    if (i == 0) {
        best_score[b] = bestv;
        best_tag[b]   = bt;
    }
}

// ---------------------------------------------------------------------------
__global__ __launch_bounds__(128) void backtrack(
    const unsigned int* __restrict__ bptrw,
    const int* __restrict__ best_tag,
    float* __restrict__ out_tags)   // d_out + 128, [B,T]
{
    const int b = threadIdx.x;
    if (b >= Bb) return;
    const long fb = (long)b * Tt;
    int tag = best_tag[b];
    out_tags[fb + Tt - 1] = (float)tag;
    #pragma unroll 8
    for (int t = Tt - 1; t >= 1; --t) {
        unsigned w = bptrw[(long)t * Bb + b];
        tag = (w >> (3 * tag)) & 7;
        out_tags[fb + t - 1] = (float)tag;
    }
}

// ---------------------------------------------------------------------------
extern "C" void kernel_launch(void* const* d_in, const int* in_sizes, int n_in,
                              void* d_out, int out_size, void* d_ws, size_t ws_size,
                              hipStream_t stream)
{
    const int*   sent    = (const int*)  d_in[0];
    const float* mask    = (const float*)d_in[1];
    const float* emb     = (const float*)d_in[2];
    const float* h0      = (const float*)d_in[3];
    const float* c0      = (const float*)d_in[4];
    const float* w_ih_l0 = (const float*)d_in[5];
    const float* w_hh_l0 = (const float*)d_in[6];
    const float* b_l0    = (const float*)d_in[7];
    const float* w_ih_l1 = (const float*)d_in[8];
    const float* w_hh_l1 = (const float*)d_in[9];
    const float* b_l1    = (const float*)d_in[10];
    const float* w_ih_l2 = (const float*)d_in[11];
    const float* w_hh_l2 = (const float*)d_in[12];
    const float* b_l2    = (const float*)d_in[13];
    const float* w_tag   = (const float*)d_in[14];
    const float* b_tag   = (const float*)d_in[15];
    const float* trans   = (const float*)d_in[16];

    float* out = (float*)d_out;
    char* ws = (char*)d_ws;

    // workspace layout (bytes)
    unsigned short* xg    = (unsigned short*)(ws);                    // 52,428,800
    float*          xa    = (float*)(ws + 52428800L);                 // 26,214,400
    float*          xb    = (float*)(ws + 78643200L);                 // 26,214,400
    unsigned short* AbR   = (unsigned short*)(ws + 104857600L);       // 41,943,040
    float*          feats = (float*)(ws + 146800640L);                //  2,097,152
    unsigned*       bptrw = (unsigned*)(ws + 148897792L);             //    262,144
    unsigned short* Wb0   = (unsigned short*)(ws + 149159936L);       //    286,720
    unsigned short* Wb1   = (unsigned short*)(ws + 149446656L);       //    114,688
    unsigned short* Wb2   = (unsigned short*)(ws + 149561344L);       //    114,688
    int*            btag  = (int*)(ws + 149676032L);                  //        512

    dim3 gridG(Mrows / 128, 7);   // 128x64 tiles over [65536, 448]

    // weight conversions (independent)
    conv_w<<<(448 * 320 + 255) / 256, 256, 0, stream>>>(w_ih_l0, Wb0, 300, 320);
    conv_w<<<(448 * 128 + 255) / 256, 256, 0, stream>>>(w_ih_l1, Wb1, 100, 128);
    conv_w<<<(448 * 128 + 255) / 256, 256, 0, stream>>>(w_ih_l2, Wb2, 100, 128);

    // layer 0
    conv_a<true><<<(Mrows * 40 + 255) / 256, 256, 0, stream>>>(emb, sent, AbR, 300, 320, 40);
    gemm_mfma<<<gridG, 256, 0, stream>>>(AbR, Wb0, b_l0, xg, 320);
    lstm_scan<<<256, 256, 0, stream>>>(xg, w_hh_l0, h0 + 0 * Bb * Hh, c0 + 0 * Bb * Hh, xa);

    // layer 1
    conv_a<false><<<(Mrows * 16 + 255) / 256, 256, 0, stream>>>(xa, nullptr, AbR, 100, 128, 16);
    gemm_mfma<<<gridG, 256, 0, stream>>>(AbR, Wb1, b_l1, xg, 128);
    lstm_scan<<<256, 256, 0, stream>>>(xg, w_hh_l1, h0 + 2 * Bb * Hh, c0 + 2 * Bb * Hh, xb);

    // layer 2
    conv_a<false><<<(Mrows * 16 + 255) / 256, 256, 0, stream>>>(xb, nullptr, AbR, 100, 128, 16);
    gemm_mfma<<<gridG, 256, 0, stream>>>(AbR, Wb2, b_l2, xg, 128);
    lstm_scan<<<256, 256, 0, stream>>>(xg, w_hh_l2, h0 + 4 * Bb * Hh, c0 + 4 * Bb * Hh, xa);

    // tag projection + viterbi + backtrace
    feats_kernel<<<Mrows * 8 / 256, 256, 0, stream>>>(xa, w_tag, b_tag, mask, feats);
    viterbi_fwd<<<Bb / 8, 64, 0, stream>>>(feats, trans, bptrw, out, btag);
    backtrack<<<1, 128, 0, stream>>>(bptrw, btag, out + Bb);
}